// Round 5
// baseline (87.828 us; speedup 1.0000x reference)
//
#include <hip/hip_runtime.h>

// Path signature depth-3, path (N=32, L=128, C=48) fp32 — fused single kernel.
//
// Math: v_t = p[t+1]-p[t], P_t[i] = p[t][i]-p[0][i],
//   G_t = P_t + v_t/2,  R_t = P_t/2 + v_t/6
//   S1 = p[127]-p[0]
//   S2[i,j]   = sum_t G_t[i] v_t[j]                       (prefix a2)
//   S3[i,j,k] = sum_t (a2prefix_t[i,j] + R_t[i] v_t[j]) v_t[k]
// t-segmented (4 segments of ~32): per segment q with local prefix a2_q:
//   S3 = sum_q [ S3local_q + a2pre_q (x) W_q ],  a2pre_q = sum_{q'<q} a2_q',
//   W_q = p[T_{q+1}] - p[T_q];  Pi seeded from path so G,R use global P. Exact.
//
// R5 changes (R4 post-mortem: LDS-issue bound ~12.8 us vs VALU 6.7 us at
// j=4 blocking; 56 FMA per 5 ds_reads):
//  1. j-tile 8 (thread = i, 8 j, 12 k): 112 FMA per 6 ds_reads -> VALU/LDS
//     balanced (~6.7 vs ~7.9 us model).
//  2. Wave count kept at 2304 (2.25/SIMD) via t-split x4 (32 iters/wave).
//  3. 2-round LDS reduction across the 4 t-segments, slot stride 52 floats
//     (16B-aligned, 2-way bank alias = free), exact a2-prefix + W fixup.
//  LDS = 53248 B -> 3 blocks/CU. VGPR target <=170 via launch_bounds(256,3).

#define N_BATCH 32
#define LPATH   128
#define T_STEPS 127
#define C       48
#define C2      2304
#define C3      110592
#define OUT_PER_N (C + C2 + C3)      // 112944
#define PATH_PER_N (LPATH * C)       // 6144
#define GROUPS 18                    // 1152 (i,jg,kc) units / 64 lanes
#define RSTRIDE 52                   // floats per reduce slot (16B-aligned)
#define LDS_FLOATS (256 * RSTRIDE)   // 13312 floats = 53248 B (v needs 6096)

__global__ __launch_bounds__(256, 3) void sig_fused(const float* __restrict__ path,
                                                    float* __restrict__ out) {
    __shared__ float lds[LDS_FLOATS];

    int bid = blockIdx.x;
    int n = bid / GROUPS;
    int g = bid - n * GROUPS;
    int tid = threadIdx.x;
    int w = tid >> 6;                // t-segment 0..3
    int lane = tid & 63;

    const float* __restrict__ pb = path + n * PATH_PER_N;

    // ---- stage v = diff(p) into LDS (coalesced float4) ----
    {
        const float4* p4 = (const float4*)pb;
        float4* v4 = (float4*)lds;
        #pragma unroll
        for (int c = 0; c < 6; ++c) {
            int idx = tid + 256 * c;
            if (idx < (T_STEPS * C) / 4) {            // 1524
                float4 a = p4[idx];
                float4 b = p4[idx + C / 4];
                v4[idx] = make_float4(b.x - a.x, b.y - a.y, b.z - a.z, b.w - a.w);
            }
        }
    }
    // S1 (once per batch), overlapped with staging
    if (g == 0 && tid < C)
        out[(long)n * OUT_PER_N + tid] = pb[(LPATH - 1) * C + tid] - pb[tid];
    __syncthreads();

    // unit U -> (i, jg, kc): U = i*24 + jg*4 + kc ; j-range = jg*8+[0,8)
    int U = g * 64 + lane;
    int i = U / 24;
    int rr = U - i * 24;
    int jg = rr >> 2;
    int kc = rr & 3;

    int T0 = w * 32;
    int T1 = (w == 3) ? T_STEPS : (T0 + 32);

    float Pi = pb[T0 * C + i] - pb[i];     // global P at segment start
    float a2[8];
    float s3[8][12];
    #pragma unroll
    for (int jj = 0; jj < 8; ++jj) {
        a2[jj] = 0.f;
        #pragma unroll
        for (int c = 0; c < 12; ++c) s3[jj][c] = 0.f;
    }

    #pragma unroll 2
    for (int t = T0; t < T1; ++t) {
        const float* base = lds + t * C;
        float4 vj0 = *(const float4*)(base + jg * 8);
        float4 vj1 = *(const float4*)(base + jg * 8 + 4);
        float4 k0  = *(const float4*)(base + kc * 12);
        float4 k1  = *(const float4*)(base + kc * 12 + 4);
        float4 k2  = *(const float4*)(base + kc * 12 + 8);
        float vi = base[i];
        float G = Pi + 0.5f * vi;
        float R = 0.5f * Pi + (1.0f / 6.0f) * vi;
        Pi += vi;
        float vja[8] = {vj0.x, vj0.y, vj0.z, vj0.w, vj1.x, vj1.y, vj1.z, vj1.w};
        float ka[12] = {k0.x, k0.y, k0.z, k0.w, k1.x, k1.y, k1.z, k1.w,
                        k2.x, k2.y, k2.z, k2.w};
        #pragma unroll
        for (int jj = 0; jj < 8; ++jj) {
            float b = a2[jj] + R * vja[jj];
            a2[jj] += G * vja[jj];
            #pragma unroll
            for (int c = 0; c < 12; ++c)
                s3[jj][c] += b * ka[c];
        }
    }

    // ---- 2-round cross-segment reduction (jj 0..3 then 4..7) ----
    long obase = (long)n * OUT_PER_N + C;
    #pragma unroll
    for (int r = 0; r < 2; ++r) {
        __syncthreads();   // r0: v reads done; r1: prev round reads done
        {
            float* dst = lds + (w * 64 + lane) * RSTRIDE;
            #pragma unroll
            for (int jj4 = 0; jj4 < 4; ++jj4) {
                int jj = r * 4 + jj4;
                *(float4*)(dst + jj4 * 12 + 0) =
                    make_float4(s3[jj][0], s3[jj][1], s3[jj][2],  s3[jj][3]);
                *(float4*)(dst + jj4 * 12 + 4) =
                    make_float4(s3[jj][4], s3[jj][5], s3[jj][6],  s3[jj][7]);
                *(float4*)(dst + jj4 * 12 + 8) =
                    make_float4(s3[jj][8], s3[jj][9], s3[jj][10], s3[jj][11]);
            }
            *(float4*)(dst + 48) =
                make_float4(a2[r * 4 + 0], a2[r * 4 + 1], a2[r * 4 + 2], a2[r * 4 + 3]);
        }
        __syncthreads();
        {
            int jj = r * 4 + w;       // this wave's output j within the round
            float acc[12];
            #pragma unroll
            for (int c = 0; c < 12; ++c) acc[c] = 0.f;
            float pre = 0.f;
            #pragma unroll
            for (int q = 0; q < 4; ++q) {
                const float* src = lds + (q * 64 + lane) * RSTRIDE;
                float4 x0 = *(const float4*)(src + w * 12);
                float4 x1 = *(const float4*)(src + w * 12 + 4);
                float4 x2 = *(const float4*)(src + w * 12 + 8);
                float a2q = src[48 + w];
                int Tlo = q * 32;
                int Thi = (q == 3) ? T_STEPS : (Tlo + 32);
                float xa[12] = {x0.x, x0.y, x0.z, x0.w, x1.x, x1.y, x1.z, x1.w,
                                x2.x, x2.y, x2.z, x2.w};
                #pragma unroll
                for (int c4 = 0; c4 < 3; ++c4) {
                    float4 lo = *(const float4*)(pb + Tlo * C + kc * 12 + c4 * 4);
                    float4 hi = *(const float4*)(pb + Thi * C + kc * 12 + c4 * 4);
                    acc[c4*4+0] += xa[c4*4+0] + pre * (hi.x - lo.x);
                    acc[c4*4+1] += xa[c4*4+1] + pre * (hi.y - lo.y);
                    acc[c4*4+2] += xa[c4*4+2] + pre * (hi.z - lo.z);
                    acc[c4*4+3] += xa[c4*4+3] + pre * (hi.w - lo.w);
                }
                pre += a2q;
            }
            // S2 (pre now = full a2 sum)
            out[obase + i * C + jg * 8 + jj] = pre;
            // S3
            float* dst = out + obase + C2 + (long)(i * C + jg * 8 + jj) * C + kc * 12;
            *(float4*)(dst + 0) = make_float4(acc[0], acc[1], acc[2],  acc[3]);
            *(float4*)(dst + 4) = make_float4(acc[4], acc[5], acc[6],  acc[7]);
            *(float4*)(dst + 8) = make_float4(acc[8], acc[9], acc[10], acc[11]);
        }
    }
}

extern "C" void kernel_launch(void* const* d_in, const int* in_sizes, int n_in,
                              void* d_out, int out_size, void* d_ws, size_t ws_size,
                              hipStream_t stream) {
    const float* path = (const float*)d_in[0];
    float* out = (float*)d_out;
    (void)d_ws; (void)ws_size;

    sig_fused<<<N_BATCH * GROUPS, 256, 0, stream>>>(path, out);
}

// Round 6
// 80.035 us; speedup vs baseline: 1.0974x; 1.0974x over previous
//
#include <hip/hip_runtime.h>

// Path signature depth-3, path (N=32, L=128, C=48) fp32 — fused single kernel.
//
// Math: v_t = p[t+1]-p[t], P_t[i] = p[t][i]-p[0][i],
//   G_t = P_t + v_t/2,  R_t = P_t/2 + v_t/6
//   S1 = p[127]-p[0]
//   S2[i,j]   = sum_t G_t[i] v_t[j]                       (prefix a2)
//   S3[i,j,k] = sum_t (a2prefix_t[i,j] + R_t[i] v_t[j]) v_t[k]
// t-segmented (4 segments of ~32): per segment q with local prefix a2_q:
//   S3 = sum_q [ S3local_q + a2pre_q (x) W_q ],  W_q = p[T_{q+1}]-p[T_q]. Exact.
//
// R6 (R5 post-mortem): R5's j8k12 math was right but the allocator broke —
// VGPR_Count=84 < 104 accumulators -> AGPR/scratch demotion (WRITE 20.5 MB =
// 14.1 + 6.4 scratch; FETCH 6.3 MB; occupancy 14%). Fixes:
//  1. __launch_bounds__(256,2): 256-reg cap (R5's (256,3) capped at 168 and
//     the allocator bailed to 84+AGPR).
//  2. #pragma unroll 1 main loop: one iter's 24 loaded floats live at a time
//     (peak ~145 regs, fits 3 waves/EU).
//  3. float4 accumulators, no scalar temp arrays.

#define N_BATCH 32
#define LPATH   128
#define T_STEPS 127
#define C       48
#define C2      2304
#define C3      110592
#define OUT_PER_N (C + C2 + C3)      // 112944
#define PATH_PER_N (LPATH * C)       // 6144
#define GROUPS 18                    // 1152 (i,jg,kc) units / 64 lanes
#define RSTRIDE 52                   // floats per reduce slot (16B-aligned)
#define LDS_FLOATS (256 * RSTRIDE)   // 13312 floats = 53248 B (v needs 6096)

__global__ __launch_bounds__(256, 2) void sig_fused(const float* __restrict__ path,
                                                    float* __restrict__ out) {
    __shared__ float lds[LDS_FLOATS];

    int bid = blockIdx.x;
    int n = bid / GROUPS;
    int g = bid - n * GROUPS;
    int tid = threadIdx.x;
    int w = tid >> 6;                // t-segment 0..3
    int lane = tid & 63;

    const float* __restrict__ pb = path + n * PATH_PER_N;

    // ---- stage v = diff(p) into LDS (coalesced float4) ----
    {
        const float4* p4 = (const float4*)pb;
        float4* v4 = (float4*)lds;
        #pragma unroll
        for (int c = 0; c < 6; ++c) {
            int idx = tid + 256 * c;
            if (idx < (T_STEPS * C) / 4) {            // 1524
                float4 a = p4[idx];
                float4 b = p4[idx + C / 4];
                v4[idx] = make_float4(b.x - a.x, b.y - a.y, b.z - a.z, b.w - a.w);
            }
        }
    }
    // S1 (once per batch), overlapped with staging
    if (g == 0 && tid < C)
        out[(long)n * OUT_PER_N + tid] = pb[(LPATH - 1) * C + tid] - pb[tid];
    __syncthreads();

    // unit U -> (i, jg, kc): U = i*24 + jg*4 + kc ; j-range = jg*8+[0,8)
    int U = g * 64 + lane;
    int i = U / 24;
    int rr = U - i * 24;
    int jg = rr >> 2;
    int kc = rr & 3;

    int T0 = w * 32;
    int T1 = (w == 3) ? T_STEPS : (T0 + 32);

    float Pi = pb[T0 * C + i] - pb[i];     // global P at segment start
    float a2[8];
    float4 s3[8][3];
    #pragma unroll
    for (int jj = 0; jj < 8; ++jj) {
        a2[jj] = 0.f;
        #pragma unroll
        for (int c = 0; c < 3; ++c) s3[jj][c] = make_float4(0.f, 0.f, 0.f, 0.f);
    }

    #pragma unroll 1
    for (int t = T0; t < T1; ++t) {
        const float* base = lds + t * C;
        float4 k0  = *(const float4*)(base + kc * 12);
        float4 k1  = *(const float4*)(base + kc * 12 + 4);
        float4 k2  = *(const float4*)(base + kc * 12 + 8);
        float4 vj0 = *(const float4*)(base + jg * 8);
        float4 vj1 = *(const float4*)(base + jg * 8 + 4);
        float vi = base[i];
        float G = Pi + 0.5f * vi;
        float R = 0.5f * Pi + (1.0f / 6.0f) * vi;
        Pi += vi;
#define SIGSTEP(jj, vjc) do {                                           \
        float b_ = a2[jj] + R * (vjc);                                  \
        a2[jj] += G * (vjc);                                            \
        s3[jj][0].x += b_ * k0.x;  s3[jj][0].y += b_ * k0.y;            \
        s3[jj][0].z += b_ * k0.z;  s3[jj][0].w += b_ * k0.w;            \
        s3[jj][1].x += b_ * k1.x;  s3[jj][1].y += b_ * k1.y;            \
        s3[jj][1].z += b_ * k1.z;  s3[jj][1].w += b_ * k1.w;            \
        s3[jj][2].x += b_ * k2.x;  s3[jj][2].y += b_ * k2.y;            \
        s3[jj][2].z += b_ * k2.z;  s3[jj][2].w += b_ * k2.w;            \
    } while (0)
        SIGSTEP(0, vj0.x);  SIGSTEP(1, vj0.y);
        SIGSTEP(2, vj0.z);  SIGSTEP(3, vj0.w);
        SIGSTEP(4, vj1.x);  SIGSTEP(5, vj1.y);
        SIGSTEP(6, vj1.z);  SIGSTEP(7, vj1.w);
#undef SIGSTEP
    }

    // ---- 2-round cross-segment reduction (jj 0..3 then 4..7) ----
    long obase = (long)n * OUT_PER_N + C;
    #pragma unroll
    for (int r = 0; r < 2; ++r) {
        __syncthreads();   // r0: v reads done; r1: prev round reads done
        {
            float* dst = lds + (w * 64 + lane) * RSTRIDE;
            #pragma unroll
            for (int jj4 = 0; jj4 < 4; ++jj4) {
                int jj = r * 4 + jj4;
                *(float4*)(dst + jj4 * 12 + 0) = s3[jj][0];
                *(float4*)(dst + jj4 * 12 + 4) = s3[jj][1];
                *(float4*)(dst + jj4 * 12 + 8) = s3[jj][2];
            }
            *(float4*)(dst + 48) =
                make_float4(a2[r * 4 + 0], a2[r * 4 + 1], a2[r * 4 + 2], a2[r * 4 + 3]);
        }
        __syncthreads();
        {
            float4 acc0 = make_float4(0.f, 0.f, 0.f, 0.f);
            float4 acc1 = make_float4(0.f, 0.f, 0.f, 0.f);
            float4 acc2 = make_float4(0.f, 0.f, 0.f, 0.f);
            float pre = 0.f;
            #pragma unroll
            for (int q = 0; q < 4; ++q) {
                const float* src = lds + (q * 64 + lane) * RSTRIDE;
                float4 x0 = *(const float4*)(src + w * 12);
                float4 x1 = *(const float4*)(src + w * 12 + 4);
                float4 x2 = *(const float4*)(src + w * 12 + 8);
                float a2q = src[48 + w];
                int Tlo = q * 32;
                int Thi = (q == 3) ? T_STEPS : (Tlo + 32);
                const float* plo = pb + Tlo * C + kc * 12;
                const float* phi = pb + Thi * C + kc * 12;
                float4 lo0 = *(const float4*)(plo + 0);
                float4 hi0 = *(const float4*)(phi + 0);
                float4 lo1 = *(const float4*)(plo + 4);
                float4 hi1 = *(const float4*)(phi + 4);
                float4 lo2 = *(const float4*)(plo + 8);
                float4 hi2 = *(const float4*)(phi + 8);
                acc0.x += x0.x + pre * (hi0.x - lo0.x);
                acc0.y += x0.y + pre * (hi0.y - lo0.y);
                acc0.z += x0.z + pre * (hi0.z - lo0.z);
                acc0.w += x0.w + pre * (hi0.w - lo0.w);
                acc1.x += x1.x + pre * (hi1.x - lo1.x);
                acc1.y += x1.y + pre * (hi1.y - lo1.y);
                acc1.z += x1.z + pre * (hi1.z - lo1.z);
                acc1.w += x1.w + pre * (hi1.w - lo1.w);
                acc2.x += x2.x + pre * (hi2.x - lo2.x);
                acc2.y += x2.y + pre * (hi2.y - lo2.y);
                acc2.z += x2.z + pre * (hi2.z - lo2.z);
                acc2.w += x2.w + pre * (hi2.w - lo2.w);
                pre += a2q;
            }
            int jj = r * 4 + w;       // this wave's output j within the round
            // S2 (pre now = full a2 sum; 4 kc lanes write identical value)
            out[obase + i * C + jg * 8 + jj] = pre;
            // S3
            float* dst = out + obase + C2 + (long)(i * C + jg * 8 + jj) * C + kc * 12;
            *(float4*)(dst + 0) = acc0;
            *(float4*)(dst + 4) = acc1;
            *(float4*)(dst + 8) = acc2;
        }
    }
}

extern "C" void kernel_launch(void* const* d_in, const int* in_sizes, int n_in,
                              void* d_out, int out_size, void* d_ws, size_t ws_size,
                              hipStream_t stream) {
    const float* path = (const float*)d_in[0];
    float* out = (float*)d_out;
    (void)d_ws; (void)ws_size;

    sig_fused<<<N_BATCH * GROUPS, 256, 0, stream>>>(path, out);
}

// Round 7
// 78.561 us; speedup vs baseline: 1.1180x; 1.0188x over previous
//
#include <hip/hip_runtime.h>

// Path signature depth-3, path (N=32, L=128, C=48) fp32 — fused single kernel.
//
// Math: v_t = p[t+1]-p[t], P_t[i] = p[t][i]-p[0][i],
//   G_t = P_t + v_t/2,  R_t = P_t/2 + v_t/6
//   S1 = p[127]-p[0]
//   S2[i,j]   = sum_t G_t[i] v_t[j]                       (prefix a2)
//   S3[i,j,k] = sum_t (a2prefix_t[i,j] + R_t[i] v_t[j]) v_t[k]
// t-split x2: segment 1 (t>=64) computed with local prefix, fixed up exactly:
//   S3 = S3_0 + S3_1^loc + a2_0 (x) W,  W = p[127]-p[64];  S2 = a2_0 + a2_1.
//
// R7 (R6 post-mortem): j8k12's 104 accumulators get AGPR-demoted (R5 showed
// VGPR=84 + 6.4 MB scratch; R6 same structure ~29 us = VALU doubled by
// accvgpr traffic). Fix: j8 x k8 tile = 80 live accs (~105 VGPR total),
// comfortably in arch VGPRs, 80 FMA per 5 ds_reads (54 cyc) -> LDS-pipe
// model 9.7 us. R4 skeleton otherwise (t-split x2, 128-thr blocks, 24.6 KB
// LDS = 6 blocks/CU cap, 1-round reduce). Grid 864 = 3.375 blocks/CU.

#define N_BATCH 32
#define LPATH   128
#define T_STEPS 127
#define C       48
#define C2      2304
#define C3      110592
#define OUT_PER_N (C + C2 + C3)      // 112944
#define PATH_PER_N (LPATH * C)       // 6144
#define GROUPS 27                    // 1728 (i,jg,kc) units / 64 lanes
#define THALF 64
#define RSTRIDE 76                   // reduce slot stride (16B-aligned)

__global__ __launch_bounds__(128, 2) void sig_fused(const float* __restrict__ path,
                                                    float* __restrict__ out) {
    __shared__ float lds[6144];      // v (6096 floats); reduce buf (64*76=4864) after

    int bid = blockIdx.x;
    int n = bid / GROUPS;
    int g = bid - n * GROUPS;
    int tid = threadIdx.x;
    int w = tid >> 6;                // t-half 0/1
    int lane = tid & 63;

    const float* __restrict__ pb = path + n * PATH_PER_N;

    // ---- stage v = diff(p) into LDS (coalesced float4) ----
    {
        const float4* p4 = (const float4*)pb;
        float4* v4 = (float4*)lds;
        #pragma unroll
        for (int c = 0; c < 12; ++c) {
            int idx = tid + 128 * c;
            if (idx < (T_STEPS * C) / 4) {            // 1524
                float4 a = p4[idx];
                float4 b = p4[idx + C / 4];
                v4[idx] = make_float4(b.x - a.x, b.y - a.y, b.z - a.z, b.w - a.w);
            }
        }
    }
    // S1 (once per batch), overlapped with staging
    if (g == 0 && tid < C)
        out[(long)n * OUT_PER_N + tid] = pb[(LPATH - 1) * C + tid] - pb[tid];
    __syncthreads();

    // unit U -> (i, jg, kc): U = i*36 + jg*6 + kc ; j = jg*8+[0,8), k = kc*8+[0,8)
    int U = g * 64 + lane;
    int i = U / 36;
    int rr = U - i * 36;
    int jg = rr / 6;
    int kc = rr - jg * 6;

    int T0 = w ? THALF : 0;
    int T1 = w ? T_STEPS : THALF;

    float Pi = w ? (pb[THALF * C + i] - pb[i]) : 0.0f;   // global P at seg start
    float a2[8];
    float4 s3[8][2];
    #pragma unroll
    for (int jj = 0; jj < 8; ++jj) {
        a2[jj] = 0.f;
        s3[jj][0] = make_float4(0.f, 0.f, 0.f, 0.f);
        s3[jj][1] = make_float4(0.f, 0.f, 0.f, 0.f);
    }

    #pragma unroll 1
    for (int t = T0; t < T1; ++t) {
        const float* base = lds + t * C;
        float4 k0  = *(const float4*)(base + kc * 8);
        float4 k1  = *(const float4*)(base + kc * 8 + 4);
        float4 vj0 = *(const float4*)(base + jg * 8);
        float4 vj1 = *(const float4*)(base + jg * 8 + 4);
        float vi = base[i];
        float G = Pi + 0.5f * vi;
        float R = 0.5f * Pi + (1.0f / 6.0f) * vi;
        Pi += vi;
#define SIGSTEP(jj, vjc) do {                                           \
        float b_ = a2[jj] + R * (vjc);                                  \
        a2[jj] += G * (vjc);                                            \
        s3[jj][0].x += b_ * k0.x;  s3[jj][0].y += b_ * k0.y;            \
        s3[jj][0].z += b_ * k0.z;  s3[jj][0].w += b_ * k0.w;            \
        s3[jj][1].x += b_ * k1.x;  s3[jj][1].y += b_ * k1.y;            \
        s3[jj][1].z += b_ * k1.z;  s3[jj][1].w += b_ * k1.w;            \
    } while (0)
        SIGSTEP(0, vj0.x);  SIGSTEP(1, vj0.y);
        SIGSTEP(2, vj0.z);  SIGSTEP(3, vj0.w);
        SIGSTEP(4, vj1.x);  SIGSTEP(5, vj1.y);
        SIGSTEP(6, vj1.z);  SIGSTEP(7, vj1.w);
#undef SIGSTEP
    }

    __syncthreads();                 // both halves done with v

    // ---- 1-round reduce: wave0 deposits, wave1 combines + fixup + store ----
    if (w == 0) {
        float* dst = lds + lane * RSTRIDE;
        #pragma unroll
        for (int jj = 0; jj < 8; ++jj) {
            *(float4*)(dst + jj * 8)     = s3[jj][0];
            *(float4*)(dst + jj * 8 + 4) = s3[jj][1];
        }
        *(float4*)(dst + 64) = make_float4(a2[0], a2[1], a2[2], a2[3]);
        *(float4*)(dst + 68) = make_float4(a2[4], a2[5], a2[6], a2[7]);
    }
    __syncthreads();

    if (w == 1) {
        const float* src = lds + lane * RSTRIDE;
        // W[k] = p[127][kc*8+c] - p[64][kc*8+c]
        float4 pe0 = *(const float4*)(pb + 127 * C + kc * 8);
        float4 pe1 = *(const float4*)(pb + 127 * C + kc * 8 + 4);
        float4 ph0 = *(const float4*)(pb + THALF * C + kc * 8);
        float4 ph1 = *(const float4*)(pb + THALF * C + kc * 8 + 4);
        float4 W0 = make_float4(pe0.x - ph0.x, pe0.y - ph0.y,
                                pe0.z - ph0.z, pe0.w - ph0.w);
        float4 W1 = make_float4(pe1.x - ph1.x, pe1.y - ph1.y,
                                pe1.z - ph1.z, pe1.w - ph1.w);

        long obase = (long)n * OUT_PER_N + C;
        #pragma unroll
        for (int jj = 0; jj < 8; ++jj) {
            float4 x0 = *(const float4*)(src + jj * 8);
            float4 x1 = *(const float4*)(src + jj * 8 + 4);
            float a20 = src[64 + jj];
            float4 r0 = make_float4(x0.x + s3[jj][0].x + a20 * W0.x,
                                    x0.y + s3[jj][0].y + a20 * W0.y,
                                    x0.z + s3[jj][0].z + a20 * W0.z,
                                    x0.w + s3[jj][0].w + a20 * W0.w);
            float4 r1 = make_float4(x1.x + s3[jj][1].x + a20 * W1.x,
                                    x1.y + s3[jj][1].y + a20 * W1.y,
                                    x1.z + s3[jj][1].z + a20 * W1.z,
                                    x1.w + s3[jj][1].w + a20 * W1.w);
            float* dst = out + obase + C2 + (long)(i * C + jg * 8 + jj) * C + kc * 8;
            *(float4*)(dst)     = r0;
            *(float4*)(dst + 4) = r1;
            if (kc == 0)
                out[obase + i * C + jg * 8 + jj] = a20 + a2[jj];   // S2
        }
    }
}

extern "C" void kernel_launch(void* const* d_in, const int* in_sizes, int n_in,
                              void* d_out, int out_size, void* d_ws, size_t ws_size,
                              hipStream_t stream) {
    const float* path = (const float*)d_in[0];
    float* out = (float*)d_out;
    (void)d_ws; (void)ws_size;

    sig_fused<<<N_BATCH * GROUPS, 128, 0, stream>>>(path, out);
}

// Round 8
// 75.880 us; speedup vs baseline: 1.1575x; 1.0353x over previous
//
#include <hip/hip_runtime.h>

// Path signature depth-3, path (N=32, L=128, C=48) fp32 — fused single kernel.
//
// Math: v_t = p[t+1]-p[t], P_t[i] = p[t][i]-p[0][i],
//   G_t = P_t + v_t/2,  R_t = P_t/2 + v_t/6
//   S1 = p[127]-p[0]
//   S2[i,j]   = sum_t G_t[i] v_t[j]                       (prefix a2)
//   S3[i,j,k] = sum_t (a2prefix_t[i,j] + R_t[i] v_t[j]) v_t[k]
// t-split x2: segment 1 (t>=64) uses local prefix, exact fixup:
//   S3 = S3_0 + S3_1^loc + a2_0 (x) W,  W = p[127]-p[64];  S2 = a2_0 + a2_1.
//
// R8 (R7 post-mortem): every round R4-R7 (~30 us) shared the same serial
// structure: 5 ds_reads -> lgkmcnt(0) -> 160 VALU cyc, at <2.3 waves/SIMD.
// ~120+ cyc LDS latency exposed per iter ~= 300 cyc/iter = the observed
// ~30 us. Fix: manual ping-pong prefetch of iteration t+1's 17 floats while
// computing t (unroll 2 turns the rotation into renames). Compiler then
// waits lgkmcnt(prev-iter) and latency hides under the FMA block even at
// 1 wave/SIMD. ~130 VGPR peak — no AGPR demotion (cap 256 via (128,2)).

#define N_BATCH 32
#define LPATH   128
#define T_STEPS 127
#define C       48
#define C2      2304
#define C3      110592
#define OUT_PER_N (C + C2 + C3)      // 112944
#define PATH_PER_N (LPATH * C)       // 6144
#define GROUPS 27                    // 1728 (i,jg,kc) units / 64 lanes
#define THALF 64
#define RSTRIDE 76                   // reduce slot stride (16B-aligned)

__global__ __launch_bounds__(128, 2) void sig_fused(const float* __restrict__ path,
                                                    float* __restrict__ out) {
    __shared__ float lds[6144];      // v (6096 floats); reduce buf (64*76=4864)

    int bid = blockIdx.x;
    int n = bid / GROUPS;
    int g = bid - n * GROUPS;
    int tid = threadIdx.x;
    int w = tid >> 6;                // t-half 0/1
    int lane = tid & 63;

    const float* __restrict__ pb = path + n * PATH_PER_N;

    // ---- stage v = diff(p) into LDS (coalesced float4) ----
    {
        const float4* p4 = (const float4*)pb;
        float4* v4 = (float4*)lds;
        #pragma unroll
        for (int c = 0; c < 12; ++c) {
            int idx = tid + 128 * c;
            if (idx < (T_STEPS * C) / 4) {            // 1524
                float4 a = p4[idx];
                float4 b = p4[idx + C / 4];
                v4[idx] = make_float4(b.x - a.x, b.y - a.y, b.z - a.z, b.w - a.w);
            }
        }
    }
    // S1 (once per batch), overlapped with staging
    if (g == 0 && tid < C)
        out[(long)n * OUT_PER_N + tid] = pb[(LPATH - 1) * C + tid] - pb[tid];
    __syncthreads();

    // unit U -> (i, jg, kc): U = i*36 + jg*6 + kc ; j = jg*8+[0,8), k = kc*8+[0,8)
    int U = g * 64 + lane;
    int i = U / 36;
    int rr = U - i * 36;
    int jg = rr / 6;
    int kc = rr - jg * 6;

    int T0 = w ? THALF : 0;
    int T1 = w ? T_STEPS : THALF;

    float Pi = w ? (pb[THALF * C + i] - pb[i]) : 0.0f;   // global P at seg start
    float a2[8];
    float4 s3[8][2];
    #pragma unroll
    for (int jj = 0; jj < 8; ++jj) {
        a2[jj] = 0.f;
        s3[jj][0] = make_float4(0.f, 0.f, 0.f, 0.f);
        s3[jj][1] = make_float4(0.f, 0.f, 0.f, 0.f);
    }

    // ---- software-pipelined main loop (ping-pong prefetch) ----
    float4 ck0, ck1, cvj0, cvj1;
    float  cvi;
    {
        const float* base = lds + T0 * C;
        ck0  = *(const float4*)(base + kc * 8);
        ck1  = *(const float4*)(base + kc * 8 + 4);
        cvj0 = *(const float4*)(base + jg * 8);
        cvj1 = *(const float4*)(base + jg * 8 + 4);
        cvi  = base[i];
    }

#define SIGCOMPUTE() do {                                               \
        float G = Pi + 0.5f * cvi;                                      \
        float R = 0.5f * Pi + (1.0f / 6.0f) * cvi;                      \
        Pi += cvi;                                                      \
        float vja[8] = {cvj0.x, cvj0.y, cvj0.z, cvj0.w,                 \
                        cvj1.x, cvj1.y, cvj1.z, cvj1.w};                \
        _Pragma("unroll")                                               \
        for (int jj = 0; jj < 8; ++jj) {                                \
            float b_ = a2[jj] + R * vja[jj];                            \
            a2[jj] += G * vja[jj];                                      \
            s3[jj][0].x += b_ * ck0.x;  s3[jj][0].y += b_ * ck0.y;      \
            s3[jj][0].z += b_ * ck0.z;  s3[jj][0].w += b_ * ck0.w;      \
            s3[jj][1].x += b_ * ck1.x;  s3[jj][1].y += b_ * ck1.y;      \
            s3[jj][1].z += b_ * ck1.z;  s3[jj][1].w += b_ * ck1.w;      \
        }                                                               \
    } while (0)

    #pragma unroll 2
    for (int t = T0; t < T1 - 1; ++t) {
        const float* nb = lds + (t + 1) * C;
        float4 nk0  = *(const float4*)(nb + kc * 8);
        float4 nk1  = *(const float4*)(nb + kc * 8 + 4);
        float4 nvj0 = *(const float4*)(nb + jg * 8);
        float4 nvj1 = *(const float4*)(nb + jg * 8 + 4);
        float  nvi  = nb[i];
        SIGCOMPUTE();
        ck0 = nk0; ck1 = nk1; cvj0 = nvj0; cvj1 = nvj1; cvi = nvi;
    }
    SIGCOMPUTE();                    // last t of this segment
#undef SIGCOMPUTE

    __syncthreads();                 // both halves done with v

    // ---- 1-round reduce: wave0 deposits, wave1 combines + fixup + store ----
    if (w == 0) {
        float* dst = lds + lane * RSTRIDE;
        #pragma unroll
        for (int jj = 0; jj < 8; ++jj) {
            *(float4*)(dst + jj * 8)     = s3[jj][0];
            *(float4*)(dst + jj * 8 + 4) = s3[jj][1];
        }
        *(float4*)(dst + 64) = make_float4(a2[0], a2[1], a2[2], a2[3]);
        *(float4*)(dst + 68) = make_float4(a2[4], a2[5], a2[6], a2[7]);
    }
    __syncthreads();

    if (w == 1) {
        const float* src = lds + lane * RSTRIDE;
        // W[k] = p[127][kc*8+c] - p[64][kc*8+c]
        float4 pe0 = *(const float4*)(pb + 127 * C + kc * 8);
        float4 pe1 = *(const float4*)(pb + 127 * C + kc * 8 + 4);
        float4 ph0 = *(const float4*)(pb + THALF * C + kc * 8);
        float4 ph1 = *(const float4*)(pb + THALF * C + kc * 8 + 4);
        float4 W0 = make_float4(pe0.x - ph0.x, pe0.y - ph0.y,
                                pe0.z - ph0.z, pe0.w - ph0.w);
        float4 W1 = make_float4(pe1.x - ph1.x, pe1.y - ph1.y,
                                pe1.z - ph1.z, pe1.w - ph1.w);

        long obase = (long)n * OUT_PER_N + C;
        #pragma unroll
        for (int jj = 0; jj < 8; ++jj) {
            float4 x0 = *(const float4*)(src + jj * 8);
            float4 x1 = *(const float4*)(src + jj * 8 + 4);
            float a20 = src[64 + jj];
            float4 r0 = make_float4(x0.x + s3[jj][0].x + a20 * W0.x,
                                    x0.y + s3[jj][0].y + a20 * W0.y,
                                    x0.z + s3[jj][0].z + a20 * W0.z,
                                    x0.w + s3[jj][0].w + a20 * W0.w);
            float4 r1 = make_float4(x1.x + s3[jj][1].x + a20 * W1.x,
                                    x1.y + s3[jj][1].y + a20 * W1.y,
                                    x1.z + s3[jj][1].z + a20 * W1.z,
                                    x1.w + s3[jj][1].w + a20 * W1.w);
            float* dst = out + obase + C2 + (long)(i * C + jg * 8 + jj) * C + kc * 8;
            *(float4*)(dst)     = r0;
            *(float4*)(dst + 4) = r1;
            if (kc == 0)
                out[obase + i * C + jg * 8 + jj] = a20 + a2[jj];   // S2
        }
    }
}

extern "C" void kernel_launch(void* const* d_in, const int* in_sizes, int n_in,
                              void* d_out, int out_size, void* d_ws, size_t ws_size,
                              hipStream_t stream) {
    const float* path = (const float*)d_in[0];
    float* out = (float*)d_out;
    (void)d_ws; (void)ws_size;

    sig_fused<<<N_BATCH * GROUPS, 128, 0, stream>>>(path, out);
}

// Round 9
// 75.447 us; speedup vs baseline: 1.1641x; 1.0057x over previous
//
#include <hip/hip_runtime.h>

// Path signature depth-3, path (N=32, L=128, C=48) fp32 — fused single kernel.
//
// Math: v_t = p[t+1]-p[t], P_t[i] = p[t][i]-p[0][i],
//   G_t = P_t + v_t/2,  R_t = P_t/2 + v_t/6
//   S1 = p[127]-p[0]
//   S2[i,j]   = sum_t G_t[i] v_t[j]                       (prefix a2)
//   S3[i,j,k] = sum_t (a2prefix_t[i,j] + R_t[i] v_t[j]) v_t[k]
// t-split x4 (segments of 32/32/32/31), Pi seeded globally per segment so
// G,R are exact; only the a2-prefix cross-term needs fixup:
//   S3 = sum_q [ S3loc_q + a2pre_q (x) W_q ],  a2pre_q = sum_{q'<q} a2loc_q',
//   W_q = p[seg_end_q] - p[seg_start_q].  S2 = sum_q a2loc_q.  Exact (R5-validated).
//
// R9 (R8 post-mortem): R4-R8 all ~24-29 us vs pipe models 8-10 us; the one
// invariant was ~1.7 waves/SIMD residency (864 blocks x 2 waves). This round
// keeps the proven j8k8 tile (~125 VGPR, no demotion) and doubles residency:
// 4 waves/block t-split with exact fixup. Reduce uses LANE-MAJOR slots
// (addr = slot*64+lane -> 2 lanes/bank = conflict-free, unlike R5's stride-52)
// in 2 rounds reusing the v buffer (27.6 KB LDS -> 5 blocks/CU cap).

#define N_BATCH 32
#define LPATH   128
#define T_STEPS 127
#define C       48
#define C2      2304
#define C3      110592
#define OUT_PER_N (C + C2 + C3)      // 112944
#define PATH_PER_N (LPATH * C)       // 6144
#define GROUPS 27                    // 1728 (i,jg,kc) units / 64 lanes
#define RSLOT 36                     // per-q slots/round: 4jj*8k + 4 a2
#define LDS_FLOATS 6912              // max(v: 6096, reduce: 3*36*64=6912)

__global__ __launch_bounds__(256, 2) void sig_fused(const float* __restrict__ path,
                                                    float* __restrict__ out) {
    __shared__ float lds[LDS_FLOATS];

    int bid = blockIdx.x;
    int n = bid / GROUPS;
    int g = bid - n * GROUPS;
    int tid = threadIdx.x;
    int q = tid >> 6;                // t-segment 0..3
    int lane = tid & 63;

    const float* __restrict__ pb = path + n * PATH_PER_N;

    // ---- stage v = diff(p) into LDS (coalesced float4) ----
    {
        const float4* p4 = (const float4*)pb;
        float4* v4 = (float4*)lds;
        #pragma unroll
        for (int c = 0; c < 6; ++c) {
            int idx = tid + 256 * c;
            if (idx < (T_STEPS * C) / 4) {            // 1524
                float4 a = p4[idx];
                float4 b = p4[idx + C / 4];
                v4[idx] = make_float4(b.x - a.x, b.y - a.y, b.z - a.z, b.w - a.w);
            }
        }
    }
    // S1 (once per batch), overlapped with staging
    if (g == 0 && tid < C)
        out[(long)n * OUT_PER_N + tid] = pb[(LPATH - 1) * C + tid] - pb[tid];
    __syncthreads();

    // unit U -> (i, jg, kc): U = i*36 + jg*6 + kc ; j = jg*8+[0,8), k = kc*8+[0,8)
    int U = g * 64 + lane;
    int i = U / 36;
    int rr = U - i * 36;
    int jg = rr / 6;
    int kc = rr - jg * 6;

    int T0 = q * 32;
    int T1 = (q == 3) ? T_STEPS : (T0 + 32);

    float Pi = pb[T0 * C + i] - pb[i];   // exact global prefix at segment start
    float a2[8];
    float4 s3[8][2];
    #pragma unroll
    for (int jj = 0; jj < 8; ++jj) {
        a2[jj] = 0.f;
        s3[jj][0] = make_float4(0.f, 0.f, 0.f, 0.f);
        s3[jj][1] = make_float4(0.f, 0.f, 0.f, 0.f);
    }

    // ---- software-pipelined main loop (ping-pong prefetch) ----
    float4 ck0, ck1, cvj0, cvj1;
    float  cvi;
    {
        const float* base = lds + T0 * C;
        ck0  = *(const float4*)(base + kc * 8);
        ck1  = *(const float4*)(base + kc * 8 + 4);
        cvj0 = *(const float4*)(base + jg * 8);
        cvj1 = *(const float4*)(base + jg * 8 + 4);
        cvi  = base[i];
    }

#define SIGCOMPUTE() do {                                               \
        float G = Pi + 0.5f * cvi;                                      \
        float R = 0.5f * Pi + (1.0f / 6.0f) * cvi;                      \
        Pi += cvi;                                                      \
        float vja[8] = {cvj0.x, cvj0.y, cvj0.z, cvj0.w,                 \
                        cvj1.x, cvj1.y, cvj1.z, cvj1.w};                \
        _Pragma("unroll")                                               \
        for (int jj = 0; jj < 8; ++jj) {                                \
            float b_ = a2[jj] + R * vja[jj];                            \
            a2[jj] += G * vja[jj];                                      \
            s3[jj][0].x += b_ * ck0.x;  s3[jj][0].y += b_ * ck0.y;      \
            s3[jj][0].z += b_ * ck0.z;  s3[jj][0].w += b_ * ck0.w;      \
            s3[jj][1].x += b_ * ck1.x;  s3[jj][1].y += b_ * ck1.y;      \
            s3[jj][1].z += b_ * ck1.z;  s3[jj][1].w += b_ * ck1.w;      \
        }                                                               \
    } while (0)

    #pragma unroll 2
    for (int t = T0; t < T1 - 1; ++t) {
        const float* nb = lds + (t + 1) * C;
        float4 nk0  = *(const float4*)(nb + kc * 8);
        float4 nk1  = *(const float4*)(nb + kc * 8 + 4);
        float4 nvj0 = *(const float4*)(nb + jg * 8);
        float4 nvj1 = *(const float4*)(nb + jg * 8 + 4);
        float  nvi  = nb[i];
        SIGCOMPUTE();
        ck0 = nk0; ck1 = nk1; cvj0 = nvj0; cvj1 = nvj1; cvi = nvi;
    }
    SIGCOMPUTE();                    // last t of this segment
#undef SIGCOMPUTE

    // ---- W vectors for the fixup (wave 3 only; L2-hot global reads) ----
    float4 W10, W11, W20, W21, W30, W31;
    if (q == 3) {
        float4 p32a = *(const float4*)(pb + 32 * C + kc * 8);
        float4 p32b = *(const float4*)(pb + 32 * C + kc * 8 + 4);
        float4 p64a = *(const float4*)(pb + 64 * C + kc * 8);
        float4 p64b = *(const float4*)(pb + 64 * C + kc * 8 + 4);
        float4 p96a = *(const float4*)(pb + 96 * C + kc * 8);
        float4 p96b = *(const float4*)(pb + 96 * C + kc * 8 + 4);
        float4 pEa  = *(const float4*)(pb + 127 * C + kc * 8);
        float4 pEb  = *(const float4*)(pb + 127 * C + kc * 8 + 4);
        W10 = make_float4(p64a.x - p32a.x, p64a.y - p32a.y, p64a.z - p32a.z, p64a.w - p32a.w);
        W11 = make_float4(p64b.x - p32b.x, p64b.y - p32b.y, p64b.z - p32b.z, p64b.w - p32b.w);
        W20 = make_float4(p96a.x - p64a.x, p96a.y - p64a.y, p96a.z - p64a.z, p96a.w - p64a.w);
        W21 = make_float4(p96b.x - p64b.x, p96b.y - p64b.y, p96b.z - p64b.z, p96b.w - p64b.w);
        W30 = make_float4(pEa.x - p96a.x, pEa.y - p96a.y, pEa.z - p96a.z, pEa.w - p96a.w);
        W31 = make_float4(pEb.x - p96b.x, pEb.y - p96b.y, pEb.z - p96b.z, pEb.w - p96b.w);
    }

    __syncthreads();                 // all waves done reading v

    // ---- 2 rounds: waves 0-2 deposit 4 jj's, wave 3 combines + stores ----
    long obase = (long)n * OUT_PER_N + C;
    #pragma unroll
    for (int r = 0; r < 2; ++r) {
        if (r) __syncthreads();      // protect previous round's reads
        if (q < 3) {
            float* dst = lds + (q * RSLOT) * 64 + lane;   // lane-major slots
            #pragma unroll
            for (int jjr = 0; jjr < 4; ++jjr) {
                int jj = r * 4 + jjr;
                dst[(jjr * 8 + 0) * 64] = s3[jj][0].x;
                dst[(jjr * 8 + 1) * 64] = s3[jj][0].y;
                dst[(jjr * 8 + 2) * 64] = s3[jj][0].z;
                dst[(jjr * 8 + 3) * 64] = s3[jj][0].w;
                dst[(jjr * 8 + 4) * 64] = s3[jj][1].x;
                dst[(jjr * 8 + 5) * 64] = s3[jj][1].y;
                dst[(jjr * 8 + 6) * 64] = s3[jj][1].z;
                dst[(jjr * 8 + 7) * 64] = s3[jj][1].w;
                dst[(32 + jjr) * 64]    = a2[jj];
            }
        }
        __syncthreads();
        if (q == 3) {
            #pragma unroll
            for (int jjr = 0; jjr < 4; ++jjr) {
                int jj = r * 4 + jjr;
                const float* s0 = lds + (0 * RSLOT) * 64 + lane;
                const float* s1 = lds + (1 * RSLOT) * 64 + lane;
                const float* s2 = lds + (2 * RSLOT) * 64 + lane;
                float a2q0 = s0[(32 + jjr) * 64];
                float a2q1 = s1[(32 + jjr) * 64];
                float a2q2 = s2[(32 + jjr) * 64];
                float pre1 = a2q0;
                float pre2 = a2q0 + a2q1;
                float pre3 = pre2 + a2q2;
                float acc[8];
                #pragma unroll
                for (int c = 0; c < 8; ++c) {
                    int sl = (jjr * 8 + c) * 64;
                    acc[c] = s0[sl] + s1[sl] + s2[sl];
                }
                acc[0] += s3[jj][0].x + pre1 * W10.x + pre2 * W20.x + pre3 * W30.x;
                acc[1] += s3[jj][0].y + pre1 * W10.y + pre2 * W20.y + pre3 * W30.y;
                acc[2] += s3[jj][0].z + pre1 * W10.z + pre2 * W20.z + pre3 * W30.z;
                acc[3] += s3[jj][0].w + pre1 * W10.w + pre2 * W20.w + pre3 * W30.w;
                acc[4] += s3[jj][1].x + pre1 * W11.x + pre2 * W21.x + pre3 * W31.x;
                acc[5] += s3[jj][1].y + pre1 * W11.y + pre2 * W21.y + pre3 * W31.y;
                acc[6] += s3[jj][1].z + pre1 * W11.z + pre2 * W21.z + pre3 * W31.z;
                acc[7] += s3[jj][1].w + pre1 * W11.w + pre2 * W21.w + pre3 * W31.w;

                float* dst = out + obase + C2 + (long)(i * C + jg * 8 + jj) * C + kc * 8;
                *(float4*)(dst)     = make_float4(acc[0], acc[1], acc[2], acc[3]);
                *(float4*)(dst + 4) = make_float4(acc[4], acc[5], acc[6], acc[7]);
                if (kc == 0)
                    out[obase + i * C + jg * 8 + jj] = pre3 + a2[jj];   // S2
            }
        }
    }
}

extern "C" void kernel_launch(void* const* d_in, const int* in_sizes, int n_in,
                              void* d_out, int out_size, void* d_ws, size_t ws_size,
                              hipStream_t stream) {
    const float* path = (const float*)d_in[0];
    float* out = (float*)d_out;
    (void)d_ws; (void)ws_size;

    sig_fused<<<N_BATCH * GROUPS, 256, 0, stream>>>(path, out);
}